// Round 4
// baseline (771.965 us; speedup 1.0000x reference)
//
#include <hip/hip_runtime.h>

#define NSTEPS 20
#define ALPHA  0.9f
#define VTH    1.0f
#define GSOMA  0.3f
#define ISCALE 0.5f

#define NOR  21
#define NORN 42
#define NLN  56
#define NPN  42
#define NKC  2000
#define NOD  34

#define TPB2 320   // 5 waves: wave 0 = producer (ORN/LN/PN), waves 1-4 = KC consumers
#define KPER 8     // KCs per consumer thread: 250 * 8 = 2000

// ===================== Fully-fused pipelined SNN =====================
// One block per batch row. Wave 0 runs the feed-forward ORN->LN->PN recurrence
// ONE STEP AHEAD of the KC consumers (legal: no KC/APL feedback into PN), writing
// the PN spike mask into a double-buffered LDS slot. Waves 1-4 are the proven
// phase2 KC/APL/logits code verbatim, reading masks from LDS instead of global.
// The single per-step __syncthreads() both phases already needed orders the
// double buffer (producer writes [t+1], consumers read [t]). This removes both
// phase1 launches, the mask global round-trip, and hides phase1's serial-chain
// latency inside phase2's ~32% idle issue slots (phase2: VALUBusy 68%).
// Exactness: producer = R0-proven dense ascending bit-extract math (same
// expression shapes, weights from LDS have identical values/order); consumer =
// proven phase2 verbatim -> bit-exact (absmax 0.0) expected.
__global__ __launch_bounds__(TPB2)
void snn_pipelined(const float* __restrict__ or_input,   // [B,21]
                   const float* __restrict__ or_gains,   // [21]
                   const float* __restrict__ mapping,    // [21,42]
                   const float* __restrict__ orn_to_pn,  // [42,42]
                   const float* __restrict__ orn_to_ln,  // [42,56]
                   const float* __restrict__ ln_to_pn,   // [56,42]
                   const float* __restrict__ pn_to_kc,   // [42,2000]
                   const float* __restrict__ kc_to_apl,  // [2000,1]
                   const float* __restrict__ apl_to_kc,  // [1,2000]
                   const float* __restrict__ dec_w,      // [2000,34]
                   const float* __restrict__ dec_b,      // [34]
                   float* __restrict__ out)              // [B,34]
{
    __shared__ float sOl[NORN * NLN];   // 9408 B
    __shared__ float sOp[NORN * NPN];   // 7056 B
    __shared__ float sLp[NLN * NPN];    // 9408 B
    __shared__ float sRed[2][4];
    __shared__ float sRed2[4 * NOD];
    __shared__ unsigned long long sMaskBuf[2];

    const int tid  = threadIdx.x;
    const int lane = tid & 63;
    const int wid  = tid >> 6;          // 0..4
    const int b    = blockIdx.x;

    // ---- stage phase1 weights to LDS (all threads) ----
    for (int i = tid; i < NORN * NLN; i += TPB2) sOl[i] = orn_to_ln[i];
    for (int i = tid; i < NORN * NPN; i += TPB2) sOp[i] = orn_to_pn[i];
    for (int i = tid; i < NLN * NPN;  i += TPB2) sLp[i] = ln_to_pn[i];
    if (tid < 8) sRed[tid >> 2][tid & 3] = 0.f;

    // ---- consumer state (waves 1-4; proven phase2 init) ----
    const int  ctid  = tid - 64;
    const int  kbase = ctid * KPER;
    const bool act   = (tid >= 64) && (kbase < NKC);   // ctid < 250
    float vd[KPER], va[KPER], cnt[KPER], wa2k[KPER], wk2a[KPER];
#pragma unroll
    for (int j = 0; j < KPER; ++j) { vd[j] = 0.f; va[j] = 0.f; cnt[j] = 0.f; }
    {
        const int idx = act ? kbase : 0;
        const float4* a4 = (const float4*)(apl_to_kc + idx);
        const float4* k4 = (const float4*)(kc_to_apl + idx);
        float4 a0 = a4[0], a1 = a4[1], k0 = k4[0], k1 = k4[1];
        const float g = act ? 1.f : 0.f;
        wa2k[0] = g * a0.x; wa2k[1] = g * a0.y; wa2k[2] = g * a0.z; wa2k[3] = g * a0.w;
        wa2k[4] = g * a1.x; wa2k[5] = g * a1.y; wa2k[6] = g * a1.z; wa2k[7] = g * a1.w;
        wk2a[0] = g * k0.x; wk2a[1] = g * k0.y; wk2a[2] = g * k0.z; wk2a[3] = g * k0.w;
        wk2a[4] = g * k1.x; wk2a[5] = g * k1.y; wk2a[6] = g * k1.z; wk2a[7] = g * k1.w;
    }

    // ---- producer state (wave 0; verbatim R0 phase1a drive compute) ----
    float v_orn = 0.f, v_ln = 0.f, v_pn = 0.f, drive = 0.f;
    const int jl = lane < NLN ? lane : 0;
    const int jp = lane < NPN ? lane : 0;
    if (wid == 0) {
        float spg = 0.f;
        if (lane < NOR) spg = log1pf(expf(or_gains[lane]));  // softplus
        const float* x = or_input + (long)b * NOR;
        const int jo = lane < NORN ? lane : 0;
#pragma unroll
        for (int i = 0; i < NOR; ++i) {
            float g = __shfl(spg, i);
            drive += x[i] * g * mapping[i * NORN + jo];
        }
        drive *= ISCALE;
    }
    __syncthreads();   // weights staged (producer reads them below)

    // ---- producer one full step: ORN -> LN -> PN mask (dense ascending, exact) ----
#define PRODUCER_STEP(MP_OUT)                                                        \
    {                                                                                \
        bool so = false;                                                             \
        if (lane < NORN) {                                                           \
            v_orn = ALPHA * v_orn + drive;                                           \
            so = (v_orn - VTH) > 0.f;                                                \
            if (so) v_orn = 0.f;                                                     \
        }                                                                            \
        const unsigned long long mO = __ballot(so);                                  \
        const unsigned int mo_lo = (unsigned int)mO;                                 \
        const unsigned int mo_hi = (unsigned int)(mO >> 32);                         \
        float aln = 0.f, apn = 0.f;                                                  \
        _Pragma("unroll")                                                            \
        for (int o = 0; o < 32; ++o) {                                               \
            const float bit = (float)((mo_lo >> o) & 1u);                            \
            aln += bit * sOl[o * NLN + jl];                                          \
            apn += bit * sOp[o * NPN + jp];                                          \
        }                                                                            \
        _Pragma("unroll")                                                            \
        for (int o = 32; o < NORN; ++o) {                                            \
            const float bit = (float)((mo_hi >> (o - 32)) & 1u);                     \
            aln += bit * sOl[o * NLN + jl];                                          \
            apn += bit * sOp[o * NPN + jp];                                          \
        }                                                                            \
        bool sl = false;                                                             \
        if (lane < NLN) {                                                            \
            v_ln = ALPHA * v_ln + aln;                                               \
            sl = (v_ln - VTH) > 0.f;                                                 \
            if (sl) v_ln = 0.f;                                                      \
        }                                                                            \
        const unsigned long long mL = __ballot(sl);                                  \
        const unsigned int ml_lo = (unsigned int)mL;                                 \
        const unsigned int ml_hi = (unsigned int)(mL >> 32);                         \
        float h = 0.f;                                                               \
        _Pragma("unroll")                                                            \
        for (int l = 0; l < 32; ++l)                                                 \
            h += (float)((ml_lo >> l) & 1u) * sLp[l * NPN + jp];                     \
        _Pragma("unroll")                                                            \
        for (int l = 32; l < NLN; ++l)                                               \
            h += (float)((ml_hi >> (l - 32)) & 1u) * sLp[l * NPN + jp];              \
        bool sp = false;                                                             \
        if (lane < NPN) {                                                            \
            v_pn = ALPHA * v_pn + apn - h;                                           \
            sp = (v_pn - VTH) > 0.f;                                                 \
            if (sp) v_pn = 0.f;                                                      \
        }                                                                            \
        MP_OUT = __ballot(sp);                                                       \
    }

    if (wid == 0) {
        unsigned long long mP;
        PRODUCER_STEP(mP)
        if (lane == 0) sMaskBuf[0] = mP;
    }
    __syncthreads();   // mask[0] ready

    for (int t = 0; t < NSTEPS; ++t) {
        if (wid == 0) {
            // produce mask for step t+1 while consumers process step t
            if (t < NSTEPS - 1) {
                unsigned long long mP;
                PRODUCER_STEP(mP)
                if (lane == 0) sMaskBuf[(t + 1) & 1] = mP;
            }
        } else {
            // ---- proven phase2 step, mask from LDS ----
            const float* rp = sRed[(t + 1) & 1];
            const float apl = fmaxf(rp[0] + rp[1] + rp[2] + rp[3], 0.f);

#pragma unroll
            for (int j = 0; j < KPER; ++j) vd[j] = ALPHA * vd[j] - apl * wa2k[j];

            unsigned long long m = sMaskBuf[t & 1];
            while (m) {
                const int p0 = __builtin_ctzll(m); m &= m - 1;
                int p1 = p0; float f1 = 0.f;
                if (m) { p1 = __builtin_ctzll(m); m &= m - 1; f1 = 1.f; }
                if (act) {
                    const float4* w0 = (const float4*)(pn_to_kc + (long)p0 * NKC + kbase);
                    const float4* w1 = (const float4*)(pn_to_kc + (long)p1 * NKC + kbase);
                    float4 a0 = w0[0], a1 = w0[1];
                    float4 b0 = w1[0], b1 = w1[1];
                    vd[0] += a0.x; vd[1] += a0.y; vd[2] += a0.z; vd[3] += a0.w;
                    vd[4] += a1.x; vd[5] += a1.y; vd[6] += a1.z; vd[7] += a1.w;
                    vd[0] += f1 * b0.x; vd[1] += f1 * b0.y; vd[2] += f1 * b0.z; vd[3] += f1 * b0.w;
                    vd[4] += f1 * b1.x; vd[5] += f1 * b1.y; vd[6] += f1 * b1.z; vd[7] += f1 * b1.w;
                }
            }

            float aplp = 0.f;
#pragma unroll
            for (int j = 0; j < KPER; ++j) {
                va[j] = ALPHA * va[j] + GSOMA * (vd[j] - va[j]);
                float s = (va[j] - VTH) > 0.f ? 1.f : 0.f;
                va[j] *= (1.f - s);
                cnt[j] += s;
                aplp += s * wk2a[j];
            }
            for (int off = 32; off > 0; off >>= 1) aplp += __shfl_xor(aplp, off, 64);
            if (lane == 0) sRed[t & 1][wid - 1] = aplp;
        }
        __syncthreads();   // orders sMaskBuf[t+1] writes vs reads AND sRed handoff
    }

    // ---- epilogue: logits (proven phase2 code; wave 0 only joins the barrier) ----
    if (wid >= 1) {
        float acc[NOD];
#pragma unroll
        for (int o = 0; o < NOD; ++o) acc[o] = 0.f;
        if (act) {
#pragma unroll
            for (int j = 0; j < KPER; ++j) {
                float r = cnt[j] / 20.0f;
                if (r != 0.f) {
                    const float* wr = dec_w + (long)(kbase + j) * NOD;
#pragma unroll
                    for (int o = 0; o < NOD; ++o) acc[o] += r * wr[o];
                }
            }
        }
#pragma unroll
        for (int o = 0; o < NOD; ++o) {
            float v = acc[o];
            for (int off = 32; off > 0; off >>= 1) v += __shfl_xor(v, off, 64);
            if (lane == 0) sRed2[(wid - 1) * NOD + o] = v;
        }
    }
    __syncthreads();
    if (tid < NOD) {
        float v = sRed2[tid] + sRed2[NOD + tid] + sRed2[2 * NOD + tid] +
                  sRed2[3 * NOD + tid] + dec_b[tid];
        out[(long)b * NOD + tid] = v;
    }
#undef PRODUCER_STEP
}

extern "C" void kernel_launch(void* const* d_in, const int* in_sizes, int n_in,
                              void* d_out, int out_size, void* d_ws, size_t ws_size,
                              hipStream_t stream) {
    (void)n_in; (void)out_size; (void)d_ws; (void)ws_size;
    const float* or_input  = (const float*)d_in[0];
    const float* or_gains  = (const float*)d_in[1];
    const float* mapping   = (const float*)d_in[2];
    const float* orn_to_pn = (const float*)d_in[3];
    const float* orn_to_ln = (const float*)d_in[4];
    const float* ln_to_pn  = (const float*)d_in[5];
    const float* pn_to_kc  = (const float*)d_in[6];
    const float* kc_to_apl = (const float*)d_in[7];
    const float* apl_to_kc = (const float*)d_in[8];
    const float* dec_w     = (const float*)d_in[9];
    const float* dec_b     = (const float*)d_in[10];
    float* out = (float*)d_out;

    const int batch = in_sizes[0] / NOR;  // 4096

    hipLaunchKernelGGL(snn_pipelined, dim3(batch), dim3(TPB2), 0, stream,
                       or_input, or_gains, mapping, orn_to_pn, orn_to_ln, ln_to_pn,
                       pn_to_kc, kc_to_apl, apl_to_kc, dec_w, dec_b, out);
}

// Round 5
// 222.660 us; speedup vs baseline: 3.4670x; 3.4670x over previous
//
#include <hip/hip_runtime.h>

#define NSTEPS 20
#define ALPHA  0.9f
#define VTH    1.0f
#define GSOMA  0.3f
#define ISCALE 0.5f

#define NOR  21
#define NORN 42
#define NLN  56
#define NPN  42
#define NKC  2000
#define NOD  34

#define TPB  256
#define KPER 8   // KCs per consumer thread: 250 * 8 = 2000

// ============ Phase 1a: ORN + LN dynamics -> {mOrn, mLn} per step ============
// (R9-proven: absmax 0.0 — verbatim restore)
__global__ __launch_bounds__(64)
void phase1a(const float* __restrict__ or_input,   // [B,21]
             const float* __restrict__ or_gains,   // [21]
             const float* __restrict__ mapping,    // [21,42]
             const float* __restrict__ orn_to_ln,  // [42,56]
             ulonglong2* __restrict__ gAB,         // [B,20] {mOrn, mLn}
             int batch)
{
    const int lane = threadIdx.x;
    const int row  = blockIdx.x;
    if (row >= batch) return;

    const int jl = lane < NLN ? lane : 0;
    float wOl[NORN];
#pragma unroll
    for (int o = 0; o < NORN; ++o) wOl[o] = orn_to_ln[o * NLN + jl];

    float spg = 0.f;
    if (lane < NOR) spg = log1pf(expf(or_gains[lane]));  // softplus

    float drive = 0.f;
    {
        const float* x = or_input + (long)row * NOR;
        const int jo = lane < NORN ? lane : 0;
#pragma unroll
        for (int i = 0; i < NOR; ++i) {
            float g = __shfl(spg, i);
            drive += x[i] * g * mapping[i * NORN + jo];
        }
        drive *= ISCALE;
    }

    float v_orn = 0.f, v_ln = 0.f;
    ulonglong2* outm = gAB + (long)row * NSTEPS;

    for (int t = 0; t < NSTEPS; ++t) {
        bool so = false;
        if (lane < NORN) {
            v_orn = ALPHA * v_orn + drive;
            so = (v_orn - VTH) > 0.f;
            if (so) v_orn = 0.f;
        }
        const unsigned long long mOrn = __ballot(so);
        const unsigned int mo_lo = (unsigned int)mOrn;
        const unsigned int mo_hi = (unsigned int)(mOrn >> 32);

        float aln = 0.f;
#pragma unroll
        for (int o = 0; o < 32; ++o) aln += (float)((mo_lo >> o) & 1u) * wOl[o];
#pragma unroll
        for (int o = 32; o < NORN; ++o) aln += (float)((mo_hi >> (o - 32)) & 1u) * wOl[o];

        bool sl = false;
        if (lane < NLN) {
            v_ln = ALPHA * v_ln + aln;
            sl = (v_ln - VTH) > 0.f;
            if (sl) v_ln = 0.f;
        }
        const unsigned long long mLn = __ballot(sl);
        if (lane == 0) outm[t] = make_ulonglong2(mOrn, mLn);
    }
}

// ============ Phase 1b: PN dynamics -> PN spike masks ============
// (R9-proven — verbatim restore)
__global__ __launch_bounds__(64)
void phase1b(const float* __restrict__ orn_to_pn,  // [42,42]
             const float* __restrict__ ln_to_pn,   // [56,42]
             const ulonglong2* __restrict__ gAB,   // [B,20]
             unsigned long long* __restrict__ gPN, // [B,20]
             int batch)
{
    const int lane = threadIdx.x;
    const int row  = blockIdx.x;
    if (row >= batch) return;

    const int jp = lane < NPN ? lane : 0;
    float wOp[NORN], wLp[NLN];
#pragma unroll
    for (int o = 0; o < NORN; ++o) wOp[o] = orn_to_pn[o * NPN + jp];
#pragma unroll
    for (int l = 0; l < NLN; ++l) wLp[l] = ln_to_pn[l * NPN + jp];

    const ulonglong2* inm = gAB + (long)row * NSTEPS;
    unsigned long long* outm = gPN + (long)row * NSTEPS;

    float v_pn = 0.f;
    ulonglong2 ab = inm[0];   // prefetch t=0

    for (int t = 0; t < NSTEPS; ++t) {
        ulonglong2 abn;
        if (t < NSTEPS - 1) abn = inm[t + 1];   // prefetch next step

        const unsigned int mo_lo = (unsigned int)ab.x;
        const unsigned int mo_hi = (unsigned int)(ab.x >> 32);
        const unsigned int ml_lo = (unsigned int)ab.y;
        const unsigned int ml_hi = (unsigned int)(ab.y >> 32);

        float apn = 0.f;
#pragma unroll
        for (int o = 0; o < 32; ++o) apn += (float)((mo_lo >> o) & 1u) * wOp[o];
#pragma unroll
        for (int o = 32; o < NORN; ++o) apn += (float)((mo_hi >> (o - 32)) & 1u) * wOp[o];

        float h = 0.f;
#pragma unroll
        for (int l = 0; l < 32; ++l) h += (float)((ml_lo >> l) & 1u) * wLp[l];
#pragma unroll
        for (int l = 32; l < NLN; ++l) h += (float)((ml_hi >> (l - 32)) & 1u) * wLp[l];

        bool sp = false;
        if (lane < NPN) {
            v_pn = ALPHA * v_pn + apn - h;
            sp = (v_pn - VTH) > 0.f;
            if (sp) v_pn = 0.f;
        }
        const unsigned long long mPn = __ballot(sp);
        if (lane == 0) outm[t] = mPn;
        ab = abn;
    }
}

// ===================== Phase 2 (dual-row): KC + APL + logits, 2 rows/block =====================
// Per-row arithmetic is VERBATIM the proven phase2 (same per-thread 8-sums, same
// 64-lane shuffle tree, same 4-partial combine) -> bit-exact per construction.
// Two rows share the per-step barrier: halves barrier cost per row and doubles
// independent work between dependency points (row B soma VALU overlaps row A's
// L2 pn_to_kc loads). Weights (wa2k/wk2a) shared across rows.
__global__ __launch_bounds__(TPB)
void phase2_dual(const unsigned long long* __restrict__ g_masks, // [B,20]
                 const float* __restrict__ pn_to_kc,  // [42,2000]
                 const float* __restrict__ kc_to_apl, // [2000,1]
                 const float* __restrict__ apl_to_kc, // [1,2000]
                 const float* __restrict__ dec_w,     // [2000,34]
                 const float* __restrict__ dec_b,     // [34]
                 float* __restrict__ out,             // [B,34]
                 int batch)
{
    __shared__ float sRedA[2][4];
    __shared__ float sRedB[2][4];
    __shared__ float sRed2[2][4 * NOD];

    const int tid  = threadIdx.x;
    const int lane = tid & 63;
    const int wid  = tid >> 6;
    const int bA   = blockIdx.x * 2;
    const int bB   = bA + 1;
    const bool hasB = (bB < batch);

    const int  kbase = tid * KPER;
    const bool act   = (kbase < NKC);   // tid < 250
    float vdA[KPER], vaA[KPER], cntA[KPER];
    float vdB[KPER], vaB[KPER], cntB[KPER];
    float wa2k[KPER], wk2a[KPER];
#pragma unroll
    for (int j = 0; j < KPER; ++j) {
        vdA[j] = 0.f; vaA[j] = 0.f; cntA[j] = 0.f;
        vdB[j] = 0.f; vaB[j] = 0.f; cntB[j] = 0.f;
    }
    {
        const int idx = act ? kbase : 0;
        const float4* a4 = (const float4*)(apl_to_kc + idx);
        const float4* k4 = (const float4*)(kc_to_apl + idx);
        float4 a0 = a4[0], a1 = a4[1], k0 = k4[0], k1 = k4[1];
        const float g = act ? 1.f : 0.f;
        wa2k[0] = g * a0.x; wa2k[1] = g * a0.y; wa2k[2] = g * a0.z; wa2k[3] = g * a0.w;
        wa2k[4] = g * a1.x; wa2k[5] = g * a1.y; wa2k[6] = g * a1.z; wa2k[7] = g * a1.w;
        wk2a[0] = g * k0.x; wk2a[1] = g * k0.y; wk2a[2] = g * k0.z; wk2a[3] = g * k0.w;
        wk2a[4] = g * k1.x; wk2a[5] = g * k1.y; wk2a[6] = g * k1.z; wk2a[7] = g * k1.w;
    }
    if (tid < 8) {
        sRedA[tid >> 2][tid & 3] = 0.f;
        sRedB[tid >> 2][tid & 3] = 0.f;
    }
    __syncthreads();

    const unsigned long long* gmA = g_masks + (long)bA * NSTEPS;
    const unsigned long long* gmB = g_masks + (long)(hasB ? bB : bA) * NSTEPS;

    for (int t = 0; t < NSTEPS; ++t) {
        // ---- row A ----
        {
            const float* rp = sRedA[(t + 1) & 1];
            const float apl = fmaxf(rp[0] + rp[1] + rp[2] + rp[3], 0.f);
#pragma unroll
            for (int j = 0; j < KPER; ++j) vdA[j] = ALPHA * vdA[j] - apl * wa2k[j];

            unsigned long long m = gmA[t];
            while (m) {
                const int p0 = __builtin_ctzll(m); m &= m - 1;
                int p1 = p0; float f1 = 0.f;
                if (m) { p1 = __builtin_ctzll(m); m &= m - 1; f1 = 1.f; }
                if (act) {
                    const float4* w0 = (const float4*)(pn_to_kc + (long)p0 * NKC + kbase);
                    const float4* w1 = (const float4*)(pn_to_kc + (long)p1 * NKC + kbase);
                    float4 a0 = w0[0], a1 = w0[1];
                    float4 b0 = w1[0], b1 = w1[1];
                    vdA[0] += a0.x; vdA[1] += a0.y; vdA[2] += a0.z; vdA[3] += a0.w;
                    vdA[4] += a1.x; vdA[5] += a1.y; vdA[6] += a1.z; vdA[7] += a1.w;
                    vdA[0] += f1 * b0.x; vdA[1] += f1 * b0.y; vdA[2] += f1 * b0.z; vdA[3] += f1 * b0.w;
                    vdA[4] += f1 * b1.x; vdA[5] += f1 * b1.y; vdA[6] += f1 * b1.z; vdA[7] += f1 * b1.w;
                }
            }

            float aplp = 0.f;
#pragma unroll
            for (int j = 0; j < KPER; ++j) {
                vaA[j] = ALPHA * vaA[j] + GSOMA * (vdA[j] - vaA[j]);
                float s = (vaA[j] - VTH) > 0.f ? 1.f : 0.f;
                vaA[j] *= (1.f - s);
                cntA[j] += s;
                aplp += s * wk2a[j];
            }
            for (int off = 32; off > 0; off >>= 1) aplp += __shfl_xor(aplp, off, 64);
            if (lane == 0) sRedA[t & 1][wid] = aplp;
        }
        // ---- row B ----
        {
            const float* rp = sRedB[(t + 1) & 1];
            const float apl = fmaxf(rp[0] + rp[1] + rp[2] + rp[3], 0.f);
#pragma unroll
            for (int j = 0; j < KPER; ++j) vdB[j] = ALPHA * vdB[j] - apl * wa2k[j];

            unsigned long long m = gmB[t];
            while (m) {
                const int p0 = __builtin_ctzll(m); m &= m - 1;
                int p1 = p0; float f1 = 0.f;
                if (m) { p1 = __builtin_ctzll(m); m &= m - 1; f1 = 1.f; }
                if (act) {
                    const float4* w0 = (const float4*)(pn_to_kc + (long)p0 * NKC + kbase);
                    const float4* w1 = (const float4*)(pn_to_kc + (long)p1 * NKC + kbase);
                    float4 a0 = w0[0], a1 = w0[1];
                    float4 b0 = w1[0], b1 = w1[1];
                    vdB[0] += a0.x; vdB[1] += a0.y; vdB[2] += a0.z; vdB[3] += a0.w;
                    vdB[4] += a1.x; vdB[5] += a1.y; vdB[6] += a1.z; vdB[7] += a1.w;
                    vdB[0] += f1 * b0.x; vdB[1] += f1 * b0.y; vdB[2] += f1 * b0.z; vdB[3] += f1 * b0.w;
                    vdB[4] += f1 * b1.x; vdB[5] += f1 * b1.y; vdB[6] += f1 * b1.z; vdB[7] += f1 * b1.w;
                }
            }

            float aplp = 0.f;
#pragma unroll
            for (int j = 0; j < KPER; ++j) {
                vaB[j] = ALPHA * vaB[j] + GSOMA * (vdB[j] - vaB[j]);
                float s = (vaB[j] - VTH) > 0.f ? 1.f : 0.f;
                vaB[j] *= (1.f - s);
                cntB[j] += s;
                aplp += s * wk2a[j];
            }
            for (int off = 32; off > 0; off >>= 1) aplp += __shfl_xor(aplp, off, 64);
            if (lane == 0) sRedB[t & 1][wid] = aplp;
        }
        __syncthreads();
    }

    // ---- epilogue: decoder for both rows (per-row code verbatim) ----
    {
        float acc[NOD];
#pragma unroll
        for (int o = 0; o < NOD; ++o) acc[o] = 0.f;
        if (act) {
#pragma unroll
            for (int j = 0; j < KPER; ++j) {
                float r = cntA[j] / 20.0f;
                if (r != 0.f) {
                    const float* wr = dec_w + (long)(kbase + j) * NOD;
#pragma unroll
                    for (int o = 0; o < NOD; ++o) acc[o] += r * wr[o];
                }
            }
        }
#pragma unroll
        for (int o = 0; o < NOD; ++o) {
            float v = acc[o];
            for (int off = 32; off > 0; off >>= 1) v += __shfl_xor(v, off, 64);
            if (lane == 0) sRed2[0][wid * NOD + o] = v;
        }
    }
    {
        float acc[NOD];
#pragma unroll
        for (int o = 0; o < NOD; ++o) acc[o] = 0.f;
        if (act) {
#pragma unroll
            for (int j = 0; j < KPER; ++j) {
                float r = cntB[j] / 20.0f;
                if (r != 0.f) {
                    const float* wr = dec_w + (long)(kbase + j) * NOD;
#pragma unroll
                    for (int o = 0; o < NOD; ++o) acc[o] += r * wr[o];
                }
            }
        }
#pragma unroll
        for (int o = 0; o < NOD; ++o) {
            float v = acc[o];
            for (int off = 32; off > 0; off >>= 1) v += __shfl_xor(v, off, 64);
            if (lane == 0) sRed2[1][wid * NOD + o] = v;
        }
    }
    __syncthreads();
    if (tid < NOD) {
        float v = sRed2[0][tid] + sRed2[0][NOD + tid] + sRed2[0][2 * NOD + tid] +
                  sRed2[0][3 * NOD + tid] + dec_b[tid];
        out[(long)bA * NOD + tid] = v;
    } else if (tid >= 64 && tid < 64 + NOD && hasB) {
        const int o = tid - 64;
        float v = sRed2[1][o] + sRed2[1][NOD + o] + sRed2[1][2 * NOD + o] +
                  sRed2[1][3 * NOD + o] + dec_b[o];
        out[(long)bB * NOD + o] = v;
    }
}

// ===================== Fallback: round-1 fused kernel (proven) =====================
__global__ __launch_bounds__(TPB)
void snn_fused(const float* __restrict__ or_input, const float* __restrict__ or_gains,
               const float* __restrict__ mapping, const float* __restrict__ orn_to_pn,
               const float* __restrict__ orn_to_ln, const float* __restrict__ ln_to_pn,
               const float* __restrict__ pn_to_kc, const float* __restrict__ kc_to_apl,
               const float* __restrict__ apl_to_kc, const float* __restrict__ dec_w,
               const float* __restrict__ dec_b, float* __restrict__ out)
{
    __shared__ float sW_ol[NORN * NLN];
    __shared__ float sW_op[NORN * NPN];
    __shared__ float sW_lp[NLN * NPN];
    __shared__ float sDrive[NORN];
    __shared__ float sSpg[NOR];
    __shared__ float sOrn[NORN];
    __shared__ float sLn[NLN];
    __shared__ float sApl;
    __shared__ float sRed[4];
    __shared__ float sRed2[4 * NOD];
    __shared__ unsigned long long sMask;

    const int tid = threadIdx.x;
    const int b   = blockIdx.x;

    for (int i = tid; i < NORN * NLN; i += TPB) sW_ol[i] = orn_to_ln[i];
    for (int i = tid; i < NORN * NPN; i += TPB) sW_op[i] = orn_to_pn[i];
    for (int i = tid; i < NLN * NPN;  i += TPB) sW_lp[i] = ln_to_pn[i];
    if (tid < NOR) sSpg[tid] = log1pf(expf(or_gains[tid]));
    if (tid == 0)  sApl = 0.f;
    __syncthreads();

    if (tid < NORN) {
        const float* x = or_input + (long)b * NOR;
        float d = 0.f;
        for (int i = 0; i < NOR; ++i) d += x[i] * sSpg[i] * mapping[i * NORN + tid];
        sDrive[tid] = d * ISCALE;
    }

    const int  kbase = tid * KPER;
    const bool act   = (kbase < NKC);
    float vd[KPER], va[KPER], cnt[KPER], wa2k[KPER], wk2a[KPER];
#pragma unroll
    for (int j = 0; j < KPER; ++j) {
        vd[j] = 0.f; va[j] = 0.f; cnt[j] = 0.f;
        wa2k[j] = act ? apl_to_kc[kbase + j] : 0.f;
        wk2a[j] = act ? kc_to_apl[kbase + j] : 0.f;
    }
    float v_orn = 0.f, v_ln = 0.f, v_pn = 0.f, v_pn_exc = 0.f;
    __syncthreads();

    for (int t = 0; t < NSTEPS; ++t) {
        if (tid < NORN) {
            v_orn = ALPHA * v_orn + sDrive[tid];
            float s = (v_orn - VTH) > 0.f ? 1.f : 0.f;
            v_orn *= (1.f - s);
            sOrn[tid] = s;
        }
        __syncthreads();
        if (tid < NLN) {
            float a = 0.f;
            for (int o = 0; o < NORN; ++o) a += sOrn[o] * sW_ol[o * NLN + tid];
            v_ln = ALPHA * v_ln + a;
            float s = (v_ln - VTH) > 0.f ? 1.f : 0.f;
            v_ln *= (1.f - s);
            sLn[tid] = s;
        } else if (tid >= 64 && tid < 64 + NPN) {
            const int j = tid - 64;
            float a = 0.f;
            for (int o = 0; o < NORN; ++o) a += sOrn[o] * sW_op[o * NPN + j];
            v_pn_exc = a;
        }
        __syncthreads();
        if (tid >= 64 && tid < 64 + NPN) {
            const int j = tid - 64;
            float inh = 0.f;
            for (int l = 0; l < NLN; ++l) inh += sLn[l] * sW_lp[l * NPN + j];
            v_pn = ALPHA * v_pn + v_pn_exc - inh;
            bool s = (v_pn - VTH) > 0.f;
            if (s) v_pn = 0.f;
            unsigned long long bal = __ballot(s);
            if (tid == 64) sMask = bal;
        }
        __syncthreads();
        {
            const float apl = sApl;
#pragma unroll
            for (int j = 0; j < KPER; ++j) vd[j] = ALPHA * vd[j] - apl * wa2k[j];
            unsigned long long m = sMask;
            while (m) {
                const int p = __builtin_ctzll(m);
                m &= m - 1;
                if (act) {
                    const float4* w = (const float4*)(pn_to_kc + (long)p * NKC + kbase);
                    float4 w0 = w[0], w1 = w[1];
                    vd[0] += w0.x; vd[1] += w0.y; vd[2] += w0.z; vd[3] += w0.w;
                    vd[4] += w1.x; vd[5] += w1.y; vd[6] += w1.z; vd[7] += w1.w;
                }
            }
            float aplp = 0.f;
#pragma unroll
            for (int j = 0; j < KPER; ++j) {
                va[j] = ALPHA * va[j] + GSOMA * (vd[j] - va[j]);
                float s = (va[j] - VTH) > 0.f ? 1.f : 0.f;
                va[j] *= (1.f - s);
                cnt[j] += s;
                aplp += s * wk2a[j];
            }
            for (int off = 32; off > 0; off >>= 1) aplp += __shfl_xor(aplp, off, 64);
            if ((tid & 63) == 0) sRed[tid >> 6] = aplp;
        }
        __syncthreads();
        if (tid == 0) {
            float a = sRed[0] + sRed[1] + sRed[2] + sRed[3];
            sApl = fmaxf(a, 0.f);
        }
    }

    float acc[NOD];
#pragma unroll
    for (int o = 0; o < NOD; ++o) acc[o] = 0.f;
    if (act) {
#pragma unroll
        for (int j = 0; j < KPER; ++j) {
            float r = cnt[j] / 20.0f;
            if (r != 0.f) {
                const float* wr = dec_w + (long)(kbase + j) * NOD;
#pragma unroll
                for (int o = 0; o < NOD; ++o) acc[o] += r * wr[o];
            }
        }
    }
#pragma unroll
    for (int o = 0; o < NOD; ++o) {
        float v = acc[o];
        for (int off = 32; off > 0; off >>= 1) v += __shfl_xor(v, off, 64);
        if ((tid & 63) == 0) sRed2[(tid >> 6) * NOD + o] = v;
    }
    __syncthreads();
    if (tid < NOD) {
        float v = sRed2[tid] + sRed2[NOD + tid] + sRed2[2 * NOD + tid] +
                  sRed2[3 * NOD + tid] + dec_b[tid];
        out[(long)b * NOD + tid] = v;
    }
}

extern "C" void kernel_launch(void* const* d_in, const int* in_sizes, int n_in,
                              void* d_out, int out_size, void* d_ws, size_t ws_size,
                              hipStream_t stream) {
    (void)n_in; (void)out_size;
    const float* or_input  = (const float*)d_in[0];
    const float* or_gains  = (const float*)d_in[1];
    const float* mapping   = (const float*)d_in[2];
    const float* orn_to_pn = (const float*)d_in[3];
    const float* orn_to_ln = (const float*)d_in[4];
    const float* ln_to_pn  = (const float*)d_in[5];
    const float* pn_to_kc  = (const float*)d_in[6];
    const float* kc_to_apl = (const float*)d_in[7];
    const float* apl_to_kc = (const float*)d_in[8];
    const float* dec_w     = (const float*)d_in[9];
    const float* dec_b     = (const float*)d_in[10];
    float* out = (float*)d_out;

    const int batch = in_sizes[0] / NOR;  // 4096
    const size_t needAB = (size_t)batch * NSTEPS * sizeof(ulonglong2);          // 1.31 MB
    const size_t needPN = (size_t)batch * NSTEPS * sizeof(unsigned long long);  // 0.66 MB

    if (ws_size >= needAB + needPN) {
        ulonglong2* gAB = (ulonglong2*)d_ws;
        unsigned long long* gPN = (unsigned long long*)((char*)d_ws + needAB);
        hipLaunchKernelGGL(phase1a, dim3(batch), dim3(64), 0, stream,
                           or_input, or_gains, mapping, orn_to_ln, gAB, batch);
        hipLaunchKernelGGL(phase1b, dim3(batch), dim3(64), 0, stream,
                           orn_to_pn, ln_to_pn, gAB, gPN, batch);
        hipLaunchKernelGGL(phase2_dual, dim3((batch + 1) / 2), dim3(TPB), 0, stream,
                           gPN, pn_to_kc, kc_to_apl, apl_to_kc, dec_w, dec_b, out, batch);
    } else {
        hipLaunchKernelGGL(snn_fused, dim3(batch), dim3(TPB), 0, stream,
                           or_input, or_gains, mapping, orn_to_pn, orn_to_ln,
                           ln_to_pn, pn_to_kc, kc_to_apl, apl_to_kc, dec_w, dec_b, out);
    }
}

// Round 6
// 210.115 us; speedup vs baseline: 3.6740x; 1.0597x over previous
//
#include <hip/hip_runtime.h>

#define NSTEPS 20
#define ALPHA  0.9f
#define VTH    1.0f
#define GSOMA  0.3f
#define ISCALE 0.5f

#define NOR  21
#define NORN 42
#define NLN  56
#define NPN  42
#define NKC  2000
#define NOD  34

#define TPB  256
#define KPER 8   // KCs per consumer thread: 250 * 8 = 2000

typedef float v2f __attribute__((ext_vector_type(2)));

// ============ Phase 1a: ORN + LN dynamics -> {mOrn, mLn} per step ============
// (proven: absmax 0.0, ~31 us — verbatim)
__global__ __launch_bounds__(64)
void phase1a(const float* __restrict__ or_input,   // [B,21]
             const float* __restrict__ or_gains,   // [21]
             const float* __restrict__ mapping,    // [21,42]
             const float* __restrict__ orn_to_ln,  // [42,56]
             ulonglong2* __restrict__ gAB,         // [B,20] {mOrn, mLn}
             int batch)
{
    const int lane = threadIdx.x;
    const int row  = blockIdx.x;
    if (row >= batch) return;

    const int jl = lane < NLN ? lane : 0;
    float wOl[NORN];
#pragma unroll
    for (int o = 0; o < NORN; ++o) wOl[o] = orn_to_ln[o * NLN + jl];

    float spg = 0.f;
    if (lane < NOR) spg = log1pf(expf(or_gains[lane]));  // softplus

    float drive = 0.f;
    {
        const float* x = or_input + (long)row * NOR;
        const int jo = lane < NORN ? lane : 0;
#pragma unroll
        for (int i = 0; i < NOR; ++i) {
            float g = __shfl(spg, i);
            drive += x[i] * g * mapping[i * NORN + jo];
        }
        drive *= ISCALE;
    }

    float v_orn = 0.f, v_ln = 0.f;
    ulonglong2* outm = gAB + (long)row * NSTEPS;

    for (int t = 0; t < NSTEPS; ++t) {
        bool so = false;
        if (lane < NORN) {
            v_orn = ALPHA * v_orn + drive;
            so = (v_orn - VTH) > 0.f;
            if (so) v_orn = 0.f;
        }
        const unsigned long long mOrn = __ballot(so);
        const unsigned int mo_lo = (unsigned int)mOrn;
        const unsigned int mo_hi = (unsigned int)(mOrn >> 32);

        float aln = 0.f;
#pragma unroll
        for (int o = 0; o < 32; ++o) aln += (float)((mo_lo >> o) & 1u) * wOl[o];
#pragma unroll
        for (int o = 32; o < NORN; ++o) aln += (float)((mo_hi >> (o - 32)) & 1u) * wOl[o];

        bool sl = false;
        if (lane < NLN) {
            v_ln = ALPHA * v_ln + aln;
            sl = (v_ln - VTH) > 0.f;
            if (sl) v_ln = 0.f;
        }
        const unsigned long long mLn = __ballot(sl);
        if (lane == 0) outm[t] = make_ulonglong2(mOrn, mLn);
    }
}

// ============ Phase 1b: PN dynamics -> PN spike masks ============
// (proven, ~31 us — verbatim)
__global__ __launch_bounds__(64)
void phase1b(const float* __restrict__ orn_to_pn,  // [42,42]
             const float* __restrict__ ln_to_pn,   // [56,42]
             const ulonglong2* __restrict__ gAB,   // [B,20]
             unsigned long long* __restrict__ gPN, // [B,20]
             int batch)
{
    const int lane = threadIdx.x;
    const int row  = blockIdx.x;
    if (row >= batch) return;

    const int jp = lane < NPN ? lane : 0;
    float wOp[NORN], wLp[NLN];
#pragma unroll
    for (int o = 0; o < NORN; ++o) wOp[o] = orn_to_pn[o * NPN + jp];
#pragma unroll
    for (int l = 0; l < NLN; ++l) wLp[l] = ln_to_pn[l * NPN + jp];

    const ulonglong2* inm = gAB + (long)row * NSTEPS;
    unsigned long long* outm = gPN + (long)row * NSTEPS;

    float v_pn = 0.f;
    ulonglong2 ab = inm[0];   // prefetch t=0

    for (int t = 0; t < NSTEPS; ++t) {
        ulonglong2 abn;
        if (t < NSTEPS - 1) abn = inm[t + 1];   // prefetch next step

        const unsigned int mo_lo = (unsigned int)ab.x;
        const unsigned int mo_hi = (unsigned int)(ab.x >> 32);
        const unsigned int ml_lo = (unsigned int)ab.y;
        const unsigned int ml_hi = (unsigned int)(ab.y >> 32);

        float apn = 0.f;
#pragma unroll
        for (int o = 0; o < 32; ++o) apn += (float)((mo_lo >> o) & 1u) * wOp[o];
#pragma unroll
        for (int o = 32; o < NORN; ++o) apn += (float)((mo_hi >> (o - 32)) & 1u) * wOp[o];

        float h = 0.f;
#pragma unroll
        for (int l = 0; l < 32; ++l) h += (float)((ml_lo >> l) & 1u) * wLp[l];
#pragma unroll
        for (int l = 32; l < NLN; ++l) h += (float)((ml_hi >> (l - 32)) & 1u) * wLp[l];

        bool sp = false;
        if (lane < NPN) {
            v_pn = ALPHA * v_pn + apn - h;
            sp = (v_pn - VTH) > 0.f;
            if (sp) v_pn = 0.f;
        }
        const unsigned long long mPn = __ballot(sp);
        if (lane == 0) outm[t] = mPn;
        ab = abn;
    }
}

// ===================== Phase 2 (packed): KC two-compartment + APL + logits =====================
// Proven single-row structure (4096 blocks, VALUBusy 68%). Two math-identical micro-opts:
// (1) PN-gather accumulates as float2 ext-vectors -> v_pk_add_f32 / v_pk_fma_f32
//     (packed f32 rounds identically to scalar; per-component order unchanged -> bit-exact).
// (2) Next-step mask prefetched (phase1b pattern) to hide the ~200cy L2-hit stall.
// Decay/soma/epilogue expressions kept verbatim scalar.
__global__ __launch_bounds__(TPB)
void phase2_pk(const unsigned long long* __restrict__ g_masks, // [B,20]
               const float* __restrict__ pn_to_kc,  // [42,2000]
               const float* __restrict__ kc_to_apl, // [2000,1]
               const float* __restrict__ apl_to_kc, // [1,2000]
               const float* __restrict__ dec_w,     // [2000,34]
               const float* __restrict__ dec_b,     // [34]
               float* __restrict__ out)             // [B,34]
{
    __shared__ float sRed[2][4];
    __shared__ float sRed2[4 * NOD];

    const int tid  = threadIdx.x;
    const int lane = tid & 63;
    const int wid  = tid >> 6;
    const int b    = blockIdx.x;

    const int  kbase = tid * KPER;
    const bool act   = (kbase < NKC);   // tid < 250
    v2f   vd2[4];
    float va[KPER], cnt[KPER], wa2k[KPER], wk2a[KPER];
#pragma unroll
    for (int k = 0; k < 4; ++k) { vd2[k] = (v2f)(0.f); }
#pragma unroll
    for (int j = 0; j < KPER; ++j) { va[j] = 0.f; cnt[j] = 0.f; }
    {
        const int idx = act ? kbase : 0;
        const float4* a4 = (const float4*)(apl_to_kc + idx);
        const float4* k4 = (const float4*)(kc_to_apl + idx);
        float4 a0 = a4[0], a1 = a4[1], k0 = k4[0], k1 = k4[1];
        const float g = act ? 1.f : 0.f;
        wa2k[0] = g * a0.x; wa2k[1] = g * a0.y; wa2k[2] = g * a0.z; wa2k[3] = g * a0.w;
        wa2k[4] = g * a1.x; wa2k[5] = g * a1.y; wa2k[6] = g * a1.z; wa2k[7] = g * a1.w;
        wk2a[0] = g * k0.x; wk2a[1] = g * k0.y; wk2a[2] = g * k0.z; wk2a[3] = g * k0.w;
        wk2a[4] = g * k1.x; wk2a[5] = g * k1.y; wk2a[6] = g * k1.z; wk2a[7] = g * k1.w;
    }
    if (tid < 8) sRed[tid >> 2][tid & 3] = 0.f;   // zero both buffers
    __syncthreads();

    const unsigned long long* gm = g_masks + (long)b * NSTEPS;
    unsigned long long mcur = gm[0];   // prefetch t=0

    for (int t = 0; t < NSTEPS; ++t) {
        unsigned long long mnext;
        if (t < NSTEPS - 1) mnext = gm[t + 1];   // prefetch next step

        const float* rp = sRed[(t + 1) & 1];
        const float apl = fmaxf(rp[0] + rp[1] + rp[2] + rp[3], 0.f);

        // decay — scalar expressions verbatim (vd[j] == vd2[j>>1][j&1])
#pragma unroll
        for (int j = 0; j < KPER; ++j)
            vd2[j >> 1][j & 1] = ALPHA * vd2[j >> 1][j & 1] - apl * wa2k[j];

        unsigned long long m = mcur;
        while (m) {
            const int p0 = __builtin_ctzll(m); m &= m - 1;
            int p1 = p0; float f1 = 0.f;
            if (m) { p1 = __builtin_ctzll(m); m &= m - 1; f1 = 1.f; }
            if (act) {
                const float4* w0 = (const float4*)(pn_to_kc + (long)p0 * NKC + kbase);
                const float4* w1 = (const float4*)(pn_to_kc + (long)p1 * NKC + kbase);
                float4 A0 = w0[0], A1 = w0[1];
                float4 B0 = w1[0], B1 = w1[1];
                v2f a0 = {A0.x, A0.y}, a1 = {A0.z, A0.w};
                v2f a2 = {A1.x, A1.y}, a3 = {A1.z, A1.w};
                v2f b0 = {B0.x, B0.y}, b1 = {B0.z, B0.w};
                v2f b2 = {B1.x, B1.y}, b3 = {B1.z, B1.w};
                // same per-component order as proven scalar: all a-adds, then f1-fmacs
                vd2[0] += a0; vd2[1] += a1; vd2[2] += a2; vd2[3] += a3;
                vd2[0] += b0 * f1; vd2[1] += b1 * f1; vd2[2] += b2 * f1; vd2[3] += b3 * f1;
            }
        }

        float aplp = 0.f;
#pragma unroll
        for (int j = 0; j < KPER; ++j) {
            va[j] = ALPHA * va[j] + GSOMA * (vd2[j >> 1][j & 1] - va[j]);
            float s = (va[j] - VTH) > 0.f ? 1.f : 0.f;
            va[j] *= (1.f - s);
            cnt[j] += s;
            aplp += s * wk2a[j];
        }
        for (int off = 32; off > 0; off >>= 1) aplp += __shfl_xor(aplp, off, 64);
        if (lane == 0) sRed[t & 1][wid] = aplp;
        __syncthreads();
        mcur = mnext;
    }

    float acc[NOD];
#pragma unroll
    for (int o = 0; o < NOD; ++o) acc[o] = 0.f;
    if (act) {
#pragma unroll
        for (int j = 0; j < KPER; ++j) {
            float r = cnt[j] / 20.0f;
            if (r != 0.f) {
                const float* wr = dec_w + (long)(kbase + j) * NOD;
#pragma unroll
                for (int o = 0; o < NOD; ++o) acc[o] += r * wr[o];
            }
        }
    }
#pragma unroll
    for (int o = 0; o < NOD; ++o) {
        float v = acc[o];
        for (int off = 32; off > 0; off >>= 1) v += __shfl_xor(v, off, 64);
        if (lane == 0) sRed2[wid * NOD + o] = v;
    }
    __syncthreads();
    if (tid < NOD) {
        float v = sRed2[tid] + sRed2[NOD + tid] + sRed2[2 * NOD + tid] +
                  sRed2[3 * NOD + tid] + dec_b[tid];
        out[(long)b * NOD + tid] = v;
    }
}

// ===================== Fallback: round-1 fused kernel (proven) =====================
__global__ __launch_bounds__(TPB)
void snn_fused(const float* __restrict__ or_input, const float* __restrict__ or_gains,
               const float* __restrict__ mapping, const float* __restrict__ orn_to_pn,
               const float* __restrict__ orn_to_ln, const float* __restrict__ ln_to_pn,
               const float* __restrict__ pn_to_kc, const float* __restrict__ kc_to_apl,
               const float* __restrict__ apl_to_kc, const float* __restrict__ dec_w,
               const float* __restrict__ dec_b, float* __restrict__ out)
{
    __shared__ float sW_ol[NORN * NLN];
    __shared__ float sW_op[NORN * NPN];
    __shared__ float sW_lp[NLN * NPN];
    __shared__ float sDrive[NORN];
    __shared__ float sSpg[NOR];
    __shared__ float sOrn[NORN];
    __shared__ float sLn[NLN];
    __shared__ float sApl;
    __shared__ float sRed[4];
    __shared__ float sRed2[4 * NOD];
    __shared__ unsigned long long sMask;

    const int tid = threadIdx.x;
    const int b   = blockIdx.x;

    for (int i = tid; i < NORN * NLN; i += TPB) sW_ol[i] = orn_to_ln[i];
    for (int i = tid; i < NORN * NPN; i += TPB) sW_op[i] = orn_to_pn[i];
    for (int i = tid; i < NLN * NPN;  i += TPB) sW_lp[i] = ln_to_pn[i];
    if (tid < NOR) sSpg[tid] = log1pf(expf(or_gains[tid]));
    if (tid == 0)  sApl = 0.f;
    __syncthreads();

    if (tid < NORN) {
        const float* x = or_input + (long)b * NOR;
        float d = 0.f;
        for (int i = 0; i < NOR; ++i) d += x[i] * sSpg[i] * mapping[i * NORN + tid];
        sDrive[tid] = d * ISCALE;
    }

    const int  kbase = tid * KPER;
    const bool act   = (kbase < NKC);
    float vd[KPER], va[KPER], cnt[KPER], wa2k[KPER], wk2a[KPER];
#pragma unroll
    for (int j = 0; j < KPER; ++j) {
        vd[j] = 0.f; va[j] = 0.f; cnt[j] = 0.f;
        wa2k[j] = act ? apl_to_kc[kbase + j] : 0.f;
        wk2a[j] = act ? kc_to_apl[kbase + j] : 0.f;
    }
    float v_orn = 0.f, v_ln = 0.f, v_pn = 0.f, v_pn_exc = 0.f;
    __syncthreads();

    for (int t = 0; t < NSTEPS; ++t) {
        if (tid < NORN) {
            v_orn = ALPHA * v_orn + sDrive[tid];
            float s = (v_orn - VTH) > 0.f ? 1.f : 0.f;
            v_orn *= (1.f - s);
            sOrn[tid] = s;
        }
        __syncthreads();
        if (tid < NLN) {
            float a = 0.f;
            for (int o = 0; o < NORN; ++o) a += sOrn[o] * sW_ol[o * NLN + tid];
            v_ln = ALPHA * v_ln + a;
            float s = (v_ln - VTH) > 0.f ? 1.f : 0.f;
            v_ln *= (1.f - s);
            sLn[tid] = s;
        } else if (tid >= 64 && tid < 64 + NPN) {
            const int j = tid - 64;
            float a = 0.f;
            for (int o = 0; o < NORN; ++o) a += sOrn[o] * sW_op[o * NPN + j];
            v_pn_exc = a;
        }
        __syncthreads();
        if (tid >= 64 && tid < 64 + NPN) {
            const int j = tid - 64;
            float inh = 0.f;
            for (int l = 0; l < NLN; ++l) inh += sLn[l] * sW_lp[l * NPN + j];
            v_pn = ALPHA * v_pn + v_pn_exc - inh;
            bool s = (v_pn - VTH) > 0.f;
            if (s) v_pn = 0.f;
            unsigned long long bal = __ballot(s);
            if (tid == 64) sMask = bal;
        }
        __syncthreads();
        {
            const float apl = sApl;
#pragma unroll
            for (int j = 0; j < KPER; ++j) vd[j] = ALPHA * vd[j] - apl * wa2k[j];
            unsigned long long m = sMask;
            while (m) {
                const int p = __builtin_ctzll(m);
                m &= m - 1;
                if (act) {
                    const float4* w = (const float4*)(pn_to_kc + (long)p * NKC + kbase);
                    float4 w0 = w[0], w1 = w[1];
                    vd[0] += w0.x; vd[1] += w0.y; vd[2] += w0.z; vd[3] += w0.w;
                    vd[4] += w1.x; vd[5] += w1.y; vd[6] += w1.z; vd[7] += w1.w;
                }
            }
            float aplp = 0.f;
#pragma unroll
            for (int j = 0; j < KPER; ++j) {
                va[j] = ALPHA * va[j] + GSOMA * (vd[j] - va[j]);
                float s = (va[j] - VTH) > 0.f ? 1.f : 0.f;
                va[j] *= (1.f - s);
                cnt[j] += s;
                aplp += s * wk2a[j];
            }
            for (int off = 32; off > 0; off >>= 1) aplp += __shfl_xor(aplp, off, 64);
            if ((tid & 63) == 0) sRed[tid >> 6] = aplp;
        }
        __syncthreads();
        if (tid == 0) {
            float a = sRed[0] + sRed[1] + sRed[2] + sRed[3];
            sApl = fmaxf(a, 0.f);
        }
    }

    float acc[NOD];
#pragma unroll
    for (int o = 0; o < NOD; ++o) acc[o] = 0.f;
    if (act) {
#pragma unroll
        for (int j = 0; j < KPER; ++j) {
            float r = cnt[j] / 20.0f;
            if (r != 0.f) {
                const float* wr = dec_w + (long)(kbase + j) * NOD;
#pragma unroll
                for (int o = 0; o < NOD; ++o) acc[o] += r * wr[o];
            }
        }
    }
#pragma unroll
    for (int o = 0; o < NOD; ++o) {
        float v = acc[o];
        for (int off = 32; off > 0; off >>= 1) v += __shfl_xor(v, off, 64);
        if ((tid & 63) == 0) sRed2[(tid >> 6) * NOD + o] = v;
    }
    __syncthreads();
    if (tid < NOD) {
        float v = sRed2[tid] + sRed2[NOD + tid] + sRed2[2 * NOD + tid] +
                  sRed2[3 * NOD + tid] + dec_b[tid];
        out[(long)b * NOD + tid] = v;
    }
}

extern "C" void kernel_launch(void* const* d_in, const int* in_sizes, int n_in,
                              void* d_out, int out_size, void* d_ws, size_t ws_size,
                              hipStream_t stream) {
    (void)n_in; (void)out_size;
    const float* or_input  = (const float*)d_in[0];
    const float* or_gains  = (const float*)d_in[1];
    const float* mapping   = (const float*)d_in[2];
    const float* orn_to_pn = (const float*)d_in[3];
    const float* orn_to_ln = (const float*)d_in[4];
    const float* ln_to_pn  = (const float*)d_in[5];
    const float* pn_to_kc  = (const float*)d_in[6];
    const float* kc_to_apl = (const float*)d_in[7];
    const float* apl_to_kc = (const float*)d_in[8];
    const float* dec_w     = (const float*)d_in[9];
    const float* dec_b     = (const float*)d_in[10];
    float* out = (float*)d_out;

    const int batch = in_sizes[0] / NOR;  // 4096
    const size_t needAB = (size_t)batch * NSTEPS * sizeof(ulonglong2);          // 1.31 MB
    const size_t needPN = (size_t)batch * NSTEPS * sizeof(unsigned long long);  // 0.66 MB

    if (ws_size >= needAB + needPN) {
        ulonglong2* gAB = (ulonglong2*)d_ws;
        unsigned long long* gPN = (unsigned long long*)((char*)d_ws + needAB);
        hipLaunchKernelGGL(phase1a, dim3(batch), dim3(64), 0, stream,
                           or_input, or_gains, mapping, orn_to_ln, gAB, batch);
        hipLaunchKernelGGL(phase1b, dim3(batch), dim3(64), 0, stream,
                           orn_to_pn, ln_to_pn, gAB, gPN, batch);
        hipLaunchKernelGGL(phase2_pk, dim3(batch), dim3(TPB), 0, stream,
                           gPN, pn_to_kc, kc_to_apl, apl_to_kc, dec_w, dec_b, out);
    } else {
        hipLaunchKernelGGL(snn_fused, dim3(batch), dim3(TPB), 0, stream,
                           or_input, or_gains, mapping, orn_to_pn, orn_to_ln,
                           ln_to_pn, pn_to_kc, kc_to_apl, apl_to_kc, dec_w, dec_b, out);
    }
}